// Round 1
// baseline (700.470 us; speedup 1.0000x reference)
//
#include <hip/hip_runtime.h>
#include <hip/hip_bf16.h>

#define NVOX 200000
#define NK   125
#define KG   5                          // k-group size (one (dz,dy) row)
#define GRID_LIN (128 * 128 * 128)

// workspace layout (bytes)
#define WT_OFF    0u                    // 125*64*64*2      = 1,024,000
#define STATS_OFF 1024000u              // 128*4            = 512
#define PFX_OFF   1024512u              // 2048*4           = 8,192
#define OLD_OFF   1032704u              // 200,000*4        = 800,000
#define FB_OFF    1832704u              // (N+1)*128        = 25,600,128  (128B aligned)
#define IDX_OFF   27432832u             // 2M*4             = 8,388,608   -> ends 35,821,440

#define F16N   (NVOX * 16)              // 3,200,000
#define WCONV_N (NK * 4096)             // 512,000
#define PREP_N (F16N + 16 + WCONV_N)    // 3,712,016

typedef short bf16x8 __attribute__((ext_vector_type(8)));
typedef float f32x4  __attribute__((ext_vector_type(4)));
typedef unsigned short u16x4 __attribute__((ext_vector_type(4)));
typedef unsigned int uint_as1 __attribute__((address_space(1)));
typedef unsigned int uint_as3 __attribute__((address_space(3)));

static __device__ __forceinline__ unsigned short f2bf(float f) {
    union { float f; unsigned int u; } v; v.f = f;
    unsigned int u = v.u;
    return (unsigned short)((u + 0x7FFFu + ((u >> 16) & 1u)) >> 16);   // RNE
}

// K1: scatter original voxel id into idx_map (pre-memset to -1)
__global__ __launch_bounds__(256) void scatter_kernel(const int* __restrict__ coords,
                                                      int* __restrict__ idx_map) {
    int p = blockIdx.x * 256 + threadIdx.x;
    if (p < NVOX) {
        int z = coords[p * 3 + 0], y = coords[p * 3 + 1], x = coords[p * 3 + 2];
        idx_map[(z << 14) | (y << 7) | x] = p;
    }
}

// K2: per-1024-cell occupancy count
__global__ __launch_bounds__(1024) void count_kernel(const int* __restrict__ idx_map,
                                                     int* __restrict__ pfx) {
    __shared__ int wsum[16];
    int i = blockIdx.x * 1024 + threadIdx.x;
    int bit = idx_map[i] >= 0 ? 1 : 0;
    unsigned long long m = __ballot(bit);
    int lane = threadIdx.x & 63, wave = threadIdx.x >> 6;
    if (lane == 0) wsum[wave] = __popcll(m);
    __syncthreads();
    if (threadIdx.x == 0) {
        int s = 0;
#pragma unroll
        for (int w = 0; w < 16; ++w) s += wsum[w];
        pfx[blockIdx.x] = s;
    }
}

// K3: exclusive scan of 2048 block counts, single block
__global__ __launch_bounds__(1024) void scan_kernel(int* __restrict__ pfx) {
    __shared__ int A[2048], B[2048];
    int t = threadIdx.x;
    A[t] = pfx[t]; A[t + 1024] = pfx[t + 1024];
    __syncthreads();
    int* src = A; int* dst = B;
    for (int off = 1; off < 2048; off <<= 1) {
        dst[t]        = src[t]        + (t >= off ? src[t - off] : 0);
        dst[t + 1024] = src[t + 1024] + src[t + 1024 - off];
        __syncthreads();
        int* tmp = src; src = dst; dst = tmp;
    }
    pfx[t]        = t ? src[t - 1] : 0;
    pfx[t + 1024] = src[t + 1023];
}

// K4: relabel cells in spatial order; idx_map[cell] <- new id; oldof[new] = old id
__global__ __launch_bounds__(1024) void relabel_kernel(const int* __restrict__ pfx,
                                                       int* __restrict__ idx_map,
                                                       int* __restrict__ oldof) {
    __shared__ int wsum[16];
    int i = blockIdx.x * 1024 + threadIdx.x;
    int old = idx_map[i];
    int bit = old >= 0 ? 1 : 0;
    unsigned long long m = __ballot(bit);
    int lane = threadIdx.x & 63, wave = threadIdx.x >> 6;
    int intra = __popcll(m & ((1ull << lane) - 1ull));
    if (lane == 0) wsum[wave] = __popcll(m);
    __syncthreads();
    int woff = 0;
    for (int w = 0; w < wave; ++w) woff += wsum[w];
    if (bit) {
        int nid = pfx[blockIdx.x] + woff + intra;
        idx_map[i] = nid;
        oldof[nid] = old;
    }
}

// K5: fused prep — feats permuted f32->bf16 (+zero row); W [125][ci][co] f32 ->
// XOR-swizzled [125][co][ci] bf16 LDS image: 16B chunk c of row co lands at c^(co&7),
// so conv's afrag ds_read_b128 spreads 8 lanes/bank-quad (= b128 floor, no conflicts).
__global__ __launch_bounds__(256) void prep_kernel(const float* __restrict__ Wt,
                                                   const float* __restrict__ feats,
                                                   const int* __restrict__ oldof,
                                                   unsigned short* __restrict__ wt,
                                                   unsigned short* __restrict__ fb) {
    int i = blockIdx.x * 256 + threadIdx.x;
    if (i < F16N) {
        int p = i >> 4, c = i & 15;
        int old = oldof[p];
        f32x4 f = *(const f32x4*)(feats + (size_t)old * 64 + c * 4);
        u16x4 u;
        u[0] = f2bf(f[0]); u[1] = f2bf(f[1]); u[2] = f2bf(f[2]); u[3] = f2bf(f[3]);
        *(u16x4*)(fb + (size_t)i * 4) = u;
    } else if (i < F16N + 16) {
        *(u16x4*)(fb + (size_t)i * 4) = (u16x4)0;
    } else if (i < PREP_N) {
        int j = i - (F16N + 16);
        int k = j >> 12, r = j & 4095;
        int co = r >> 6, ci = r & 63;
        int dst = (co << 6) | ((((ci >> 3) ^ (co & 7)) << 3) | (ci & 7));
        wt[(k << 12) + dst] = f2bf(Wt[(k << 12) + (ci << 6) + co]);
    }
}

// stage one 8KB W slice into LDS slot: 256 threads x 2 x 16B, wave-contiguous
static __device__ __forceinline__ void stage_w(const unsigned short* wt, int k,
                                               unsigned short* dst, int tid) {
    const unsigned short* src = wt + ((size_t)k << 12) + tid * 8;
    __builtin_amdgcn_global_load_lds((const uint_as1*)(const void*)src,
                                     (uint_as3*)(void*)(dst + tid * 8), 16, 0, 0);
    __builtin_amdgcn_global_load_lds((const uint_as1*)(const void*)(src + 2048),
                                     (uint_as3*)(void*)(dst + tid * 8 + 2048), 16, 0, 0);
}

// Conv over spatially-relabeled voxels. Block = 256 consecutive (spatial) voxels,
// XCD-swizzled so each XCD owns a contiguous label slab (L2-resident window).
// K-loop in 25 groups of 5 (fixed dz,dy; dx=-2..2): per group, stage 5 W slices +
// probe 5 consecutive idx_map cells, ONE barrier, then 5 k's of barrier-free
// MFMA compute. Per kk: ALL 8 feature gathers + all 8 A-frags issued up front
// (loads unconditional; dead lanes hit the L1-resident zero row), next kk's jt4
// prefetched, then a sched_barrier pins the loads before the per-t conditional
// MFMA blocks -> ONE exposed gather latency per kk instead of four.
__global__ __launch_bounds__(256, 3) void conv_kernel(
    const int* __restrict__ coords, const unsigned short* __restrict__ fb,
    const unsigned short* __restrict__ wt, const int* __restrict__ idx_map,
    const int* __restrict__ oldof,
    float* __restrict__ out, float* __restrict__ stats) {
    __shared__ unsigned short lds_w[KG * 4096];   // 40 KB, 5 slices
    __shared__ int lds_nbr[KG * 256];             // 5 KB, transposed [kk][w][l15][t]

    const int vblk = (blockIdx.x & 7) * 98 + (blockIdx.x >> 3);
    const int vbase = vblk * 256;
    if (vbase >= NVOX) return;

    const int tid  = threadIdx.x;
    const int wave = tid >> 6;
    const int lane = tid & 63;
    const int g    = lane >> 4;
    const int l15  = lane & 15;
    const int vox  = vbase + tid;
    const bool live = vox < NVOX;

    int z = 0, y = 0, x = 0;
    if (live) {
        int old = oldof[vox];
        z = coords[old * 3 + 0]; y = coords[old * 3 + 1]; x = coords[old * 3 + 2];
    }
    const int slot = (tid & ~63) | ((tid & 15) << 2) | ((tid >> 4) & 3);
    const int sw0 = ((g    ) ^ (l15 & 7)) << 4;   // swizzled chunk offset, s=0
    const int sw1 = ((g + 4) ^ (l15 & 7)) << 4;   // s=1

    f32x4 acc[4][4];
#pragma unroll
    for (int a = 0; a < 4; ++a)
#pragma unroll
        for (int b = 0; b < 4; ++b) acc[a][b] = (f32x4)0.0f;

    const char* fbp = (const char*)fb;

    for (int grp = 0; grp < NK / KG; ++grp) {
        __syncthreads();                          // prev group's readers done
        // stage this group's 5 W slices
#pragma unroll
        for (int kk = 0; kk < KG; ++kk)
            stage_w(wt, grp * KG + kk, &lds_w[kk * 4096], tid);
        // probe 5 consecutive cells: dz,dy fixed per group, dx = -2..2
        const int dz = grp / 5 - 2, dy = grp % 5 - 2;
        const int nz = z + dz, ny = y + dy;
        const bool rowok = live && ((unsigned)nz < 128u) && ((unsigned)ny < 128u);
        const int base = (nz << 14) | (ny << 7);
#pragma unroll
        for (int kk = 0; kk < KG; ++kk) {
            int nx = x + kk - 2;
            int j = NVOX;
            if (rowok && ((unsigned)nx < 128u)) {
                int t = idx_map[base | nx];
                if (t >= 0) j = t;
            }
            lds_nbr[kk * 256 + slot] = j;
        }
        __syncthreads();                          // stage + nbr visible

        int4 jt4 = *(const int4*)&lds_nbr[wave * 64 + l15 * 4];
#pragma unroll
        for (int kk = 0; kk < KG; ++kk) {
            const int jt[4] = {jt4.x, jt4.y, jt4.z, jt4.w};

            // batch-issue ALL 8 feature gathers for this kk (unconditional;
            // dead lanes read the zero row, which stays L1-resident)
            bf16x8 b0f[4], b1f[4];
#pragma unroll
            for (int t = 0; t < 4; ++t) {
                const char* rp = fbp + ((size_t)(unsigned)jt[t] << 7) + (g << 4);
                b0f[t] = *(const bf16x8*)(rp);
                b1f[t] = *(const bf16x8*)(rp + 64);
            }
            // prefetch next kk's neighbor ids (LDS latency hides under MFMAs)
            if (kk + 1 < KG)
                jt4 = *(const int4*)&lds_nbr[(kk + 1) * 256 + wave * 64 + l15 * 4];

            // A fragments from LDS (swizzled, conflict-free)
            const char* wb = (const char*)&lds_w[kk * 4096];
            bf16x8 af0[4], af1[4];
#pragma unroll
            for (int a = 0; a < 4; ++a) {
                af0[a] = *(const bf16x8*)(wb + (((a * 16 + l15) << 7) | sw0));
                af1[a] = *(const bf16x8*)(wb + (((a * 16 + l15) << 7) | sw1));
            }

            // pin all loads above the conditional MFMA blocks (prevents LLVM
            // from sinking gathers back into the branches -> re-serializing)
            __builtin_amdgcn_sched_barrier(0);

#pragma unroll
            for (int t = 0; t < 4; ++t) {
                if (__any(jt[t] != NVOX)) {       // wave-uniform zero-tile skip
#pragma unroll
                    for (int a = 0; a < 4; ++a) {
                        acc[a][t] = __builtin_amdgcn_mfma_f32_16x16x32_bf16(af0[a], b0f[t], acc[a][t], 0, 0, 0);
                        acc[a][t] = __builtin_amdgcn_mfma_f32_16x16x32_bf16(af1[a], b1f[t], acc[a][t], 0, 0, 0);
                    }
                }
            }
        }
    }

    // epilogue: scatter rows back to ORIGINAL voxel order (bias cancels under BN)
#pragma unroll
    for (int b = 0; b < 4; ++b) {
        int v = vbase + wave * 64 + b * 16 + l15;
        if (v < NVOX) {
            int o = oldof[v];
#pragma unroll
            for (int a = 0; a < 4; ++a)
                *(f32x4*)(out + (size_t)o * 64 + a * 16 + g * 4) = acc[a][b];
        }
    }

    // BN batch-stat partials over this wave's 64 voxels
    float s1[16], s2[16];
#pragma unroll
    for (int a = 0; a < 4; ++a)
#pragma unroll
        for (int r = 0; r < 4; ++r) {
            float s = 0.f, q = 0.f;
#pragma unroll
            for (int b = 0; b < 4; ++b) { float xv = acc[a][b][r]; s += xv; q += xv * xv; }
            s1[a * 4 + r] = s; s2[a * 4 + r] = q;
        }
#pragma unroll
    for (int m = 1; m < 16; m <<= 1) {
#pragma unroll
        for (int i = 0; i < 16; ++i) {
            s1[i] += __shfl_xor(s1[i], m, 64);
            s2[i] += __shfl_xor(s2[i], m, 64);
        }
    }
    if (l15 == 0) {
#pragma unroll
        for (int a = 0; a < 4; ++a)
#pragma unroll
            for (int r = 0; r < 4; ++r) {
                int co = a * 16 + g * 4 + r;
                atomicAdd(&stats[co],      s1[a * 4 + r]);
                atomicAdd(&stats[64 + co], s2[a * 4 + r]);
            }
    }
}

__global__ __launch_bounds__(256) void finalize_kernel(float* __restrict__ out,
                                                       const float* __restrict__ stats,
                                                       const float* __restrict__ gamma,
                                                       const float* __restrict__ beta) {
    int i = blockIdx.x * 256 + threadIdx.x;
    if (i >= NVOX * 16) return;
    int cg = (i & 15) * 4;
    f32x4 v = *(f32x4*)(out + (size_t)i * 4);
    f32x4 r;
#pragma unroll
    for (int c = 0; c < 4; ++c) {
        int co = cg + c;
        float mean = stats[co] * (1.0f / NVOX);
        float var  = stats[64 + co] * (1.0f / NVOX) - mean * mean;
        float sc   = rsqrtf(var + 1e-5f) * gamma[co];
        float sh   = beta[co] - mean * sc;
        float yv   = v[c] * sc + sh;
        r[c] = yv > 0.f ? yv : expm1f(yv);
    }
    *(f32x4*)(out + (size_t)i * 4) = r;
}

extern "C" void kernel_launch(void* const* d_in, const int* in_sizes, int n_in,
                              void* d_out, int out_size, void* d_ws, size_t ws_size,
                              hipStream_t stream) {
    const float* feats  = (const float*)d_in[0];
    const int*   coords = (const int*)d_in[1];
    const float* Wt     = (const float*)d_in[2];
    // d_in[3] = bias: unused — cancels exactly under training-mode BN
    const float* gamma  = (const float*)d_in[4];
    const float* beta   = (const float*)d_in[5];
    float* out = (float*)d_out;
    char*  ws  = (char*)d_ws;

    unsigned short* wt  = (unsigned short*)(ws + WT_OFF);
    float* stats        = (float*)(ws + STATS_OFF);
    int*   pfx          = (int*)(ws + PFX_OFF);
    int*   oldof        = (int*)(ws + OLD_OFF);
    unsigned short* fb  = (unsigned short*)(ws + FB_OFF);
    int*   idx_map      = (int*)(ws + IDX_OFF);

    hipMemsetAsync(idx_map, 0xFF, (size_t)GRID_LIN * 4, stream);  // -1
    hipMemsetAsync(stats, 0, 128 * 4, stream);

    scatter_kernel<<<(NVOX + 255) / 256, 256, 0, stream>>>(coords, idx_map);
    count_kernel<<<GRID_LIN / 1024, 1024, 0, stream>>>(idx_map, pfx);
    scan_kernel<<<1, 1024, 0, stream>>>(pfx);
    relabel_kernel<<<GRID_LIN / 1024, 1024, 0, stream>>>(pfx, idx_map, oldof);
    prep_kernel<<<(PREP_N + 255) / 256, 256, 0, stream>>>(Wt, feats, oldof, wt, fb);
    conv_kernel<<<784, 256, 0, stream>>>(coords, fb, wt, idx_map, oldof, out, stats);
    finalize_kernel<<<12500, 256, 0, stream>>>(out, stats, gamma, beta);
}

// Round 2
// 641.117 us; speedup vs baseline: 1.0926x; 1.0926x over previous
//
#include <hip/hip_runtime.h>
#include <hip/hip_bf16.h>

#define NVOX 200000
#define NK   125
#define KG   5                          // k-group size (one (dz,dy) row)
#define GRID_LIN (128 * 128 * 128)

// workspace layout (bytes)
#define WT_OFF    0u                    // 125*64*64*2      = 1,024,000
#define STATS_OFF 1024000u              // 128*4            = 512
#define PFX_OFF   1024512u              // 2048*4           = 8,192
#define OLD_OFF   1032704u              // 200,000*4        = 800,000
#define FB_OFF    1832704u              // (N+1)*128        = 25,600,128  (128B aligned)
#define IDX_OFF   27432832u             // 2M*4             = 8,388,608   -> ends 35,821,440

#define F16N   (NVOX * 16)              // 3,200,000
#define WCONV_N (NK * 4096)             // 512,000
#define PREP_N (F16N + 16 + WCONV_N)    // 3,712,016

typedef short bf16x8 __attribute__((ext_vector_type(8)));
typedef float f32x4  __attribute__((ext_vector_type(4)));
typedef unsigned short u16x4 __attribute__((ext_vector_type(4)));
typedef unsigned int uint_as1 __attribute__((address_space(1)));
typedef unsigned int uint_as3 __attribute__((address_space(3)));

static __device__ __forceinline__ unsigned short f2bf(float f) {
    union { float f; unsigned int u; } v; v.f = f;
    unsigned int u = v.u;
    return (unsigned short)((u + 0x7FFFu + ((u >> 16) & 1u)) >> 16);   // RNE
}

// K1: scatter original voxel id into idx_map (pre-memset to -1)
__global__ __launch_bounds__(256) void scatter_kernel(const int* __restrict__ coords,
                                                      int* __restrict__ idx_map) {
    int p = blockIdx.x * 256 + threadIdx.x;
    if (p < NVOX) {
        int z = coords[p * 3 + 0], y = coords[p * 3 + 1], x = coords[p * 3 + 2];
        idx_map[(z << 14) | (y << 7) | x] = p;
    }
}

// K2: per-1024-cell occupancy count
__global__ __launch_bounds__(1024) void count_kernel(const int* __restrict__ idx_map,
                                                     int* __restrict__ pfx) {
    __shared__ int wsum[16];
    int i = blockIdx.x * 1024 + threadIdx.x;
    int bit = idx_map[i] >= 0 ? 1 : 0;
    unsigned long long m = __ballot(bit);
    int lane = threadIdx.x & 63, wave = threadIdx.x >> 6;
    if (lane == 0) wsum[wave] = __popcll(m);
    __syncthreads();
    if (threadIdx.x == 0) {
        int s = 0;
#pragma unroll
        for (int w = 0; w < 16; ++w) s += wsum[w];
        pfx[blockIdx.x] = s;
    }
}

// K3: exclusive scan of 2048 block counts, single block
__global__ __launch_bounds__(1024) void scan_kernel(int* __restrict__ pfx) {
    __shared__ int A[2048], B[2048];
    int t = threadIdx.x;
    A[t] = pfx[t]; A[t + 1024] = pfx[t + 1024];
    __syncthreads();
    int* src = A; int* dst = B;
    for (int off = 1; off < 2048; off <<= 1) {
        dst[t]        = src[t]        + (t >= off ? src[t - off] : 0);
        dst[t + 1024] = src[t + 1024] + src[t + 1024 - off];
        __syncthreads();
        int* tmp = src; src = dst; dst = tmp;
    }
    pfx[t]        = t ? src[t - 1] : 0;
    pfx[t + 1024] = src[t + 1023];
}

// K4: relabel cells in spatial order; idx_map[cell] <- new id; oldof[new] = old id
__global__ __launch_bounds__(1024) void relabel_kernel(const int* __restrict__ pfx,
                                                       int* __restrict__ idx_map,
                                                       int* __restrict__ oldof) {
    __shared__ int wsum[16];
    int i = blockIdx.x * 1024 + threadIdx.x;
    int old = idx_map[i];
    int bit = old >= 0 ? 1 : 0;
    unsigned long long m = __ballot(bit);
    int lane = threadIdx.x & 63, wave = threadIdx.x >> 6;
    int intra = __popcll(m & ((1ull << lane) - 1ull));
    if (lane == 0) wsum[wave] = __popcll(m);
    __syncthreads();
    int woff = 0;
    for (int w = 0; w < wave; ++w) woff += wsum[w];
    if (bit) {
        int nid = pfx[blockIdx.x] + woff + intra;
        idx_map[i] = nid;
        oldof[nid] = old;
    }
}

// K5: fused prep — feats permuted f32->bf16 (+zero row); W [125][ci][co] f32 ->
// XOR-swizzled [125][co][ci] bf16 LDS image: 16B chunk c of row co lands at c^(co&7),
// so conv's afrag ds_read_b128 spreads 8 lanes/bank-quad (= b128 floor, no conflicts).
__global__ __launch_bounds__(256) void prep_kernel(const float* __restrict__ Wt,
                                                   const float* __restrict__ feats,
                                                   const int* __restrict__ oldof,
                                                   unsigned short* __restrict__ wt,
                                                   unsigned short* __restrict__ fb) {
    int i = blockIdx.x * 256 + threadIdx.x;
    if (i < F16N) {
        int p = i >> 4, c = i & 15;
        int old = oldof[p];
        f32x4 f = *(const f32x4*)(feats + (size_t)old * 64 + c * 4);
        u16x4 u;
        u[0] = f2bf(f[0]); u[1] = f2bf(f[1]); u[2] = f2bf(f[2]); u[3] = f2bf(f[3]);
        *(u16x4*)(fb + (size_t)i * 4) = u;
    } else if (i < F16N + 16) {
        *(u16x4*)(fb + (size_t)i * 4) = (u16x4)0;
    } else if (i < PREP_N) {
        int j = i - (F16N + 16);
        int k = j >> 12, r = j & 4095;
        int co = r >> 6, ci = r & 63;
        int dst = (co << 6) | ((((ci >> 3) ^ (co & 7)) << 3) | (ci & 7));
        wt[(k << 12) + dst] = f2bf(Wt[(k << 12) + (ci << 6) + co]);
    }
}

// stage one 8KB W slice into LDS slot: 256 threads x 2 x 16B, wave-contiguous
static __device__ __forceinline__ void stage_w(const unsigned short* wt, int k,
                                               unsigned short* dst, int tid) {
    const unsigned short* src = wt + ((size_t)k << 12) + tid * 8;
    __builtin_amdgcn_global_load_lds((const uint_as1*)(const void*)src,
                                     (uint_as3*)(void*)(dst + tid * 8), 16, 0, 0);
    __builtin_amdgcn_global_load_lds((const uint_as1*)(const void*)(src + 2048),
                                     (uint_as3*)(void*)(dst + tid * 8 + 2048), 16, 0, 0);
}

// Conv over spatially-relabeled voxels. Block = 256 consecutive (spatial) voxels,
// XCD-swizzled so each XCD owns a contiguous label slab (L2-resident window).
// Per-block GROUP ROTATION (ge = (grp+vblk)%25): k-sum is commutative, so each
// block walks the 25 (dz,dy) groups from a different start -> co-resident blocks
// de-lockstep, one block's VMEM phase hides under another's MFMA phase.
// Per group: stage 5 W slices + probe 5 cells, ONE barrier, then 5 kk with an
// EXPLICIT 1-deep B-gather double-buffer (bb[2], jj[2]): kk+1's 8 gathers issue
// before kk's MFMA cluster -> counted vmcnt waits, one exposed latency per group.
// launch_bounds(256,2) raises the unified reg cap so the prefetch actually fits
// (round-1's 84-VGPR allocation had zero headroom to hoist -> full serial).
__global__ __launch_bounds__(256, 2) void conv_kernel(
    const int* __restrict__ coords, const unsigned short* __restrict__ fb,
    const unsigned short* __restrict__ wt, const int* __restrict__ idx_map,
    const int* __restrict__ oldof,
    float* __restrict__ out, float* __restrict__ stats) {
    __shared__ unsigned short lds_w[KG * 4096];   // 40 KB, 5 slices
    __shared__ int lds_nbr[KG * 256];             // 5 KB, transposed [kk][w][l15][t]

    const int vblk = (blockIdx.x & 7) * 98 + (blockIdx.x >> 3);
    const int vbase = vblk * 256;
    if (vbase >= NVOX) return;

    const int tid  = threadIdx.x;
    const int wave = tid >> 6;
    const int lane = tid & 63;
    const int g    = lane >> 4;
    const int l15  = lane & 15;
    const int vox  = vbase + tid;
    const bool live = vox < NVOX;
    const int rot  = vblk % 25;                   // per-block group phase offset

    int z = 0, y = 0, x = 0;
    if (live) {
        int old = oldof[vox];
        z = coords[old * 3 + 0]; y = coords[old * 3 + 1]; x = coords[old * 3 + 2];
    }
    const int slot = (tid & ~63) | ((tid & 15) << 2) | ((tid >> 4) & 3);
    const int sw0 = ((g    ) ^ (l15 & 7)) << 4;   // swizzled chunk offset, s=0
    const int sw1 = ((g + 4) ^ (l15 & 7)) << 4;   // s=1

    f32x4 acc[4][4];
#pragma unroll
    for (int a = 0; a < 4; ++a)
#pragma unroll
        for (int b = 0; b < 4; ++b) acc[a][b] = (f32x4)0.0f;

    const char* fbp = (const char*)fb;

    for (int grp = 0; grp < NK / KG; ++grp) {
        int ge = grp + rot; if (ge >= 25) ge -= 25;    // rotated group id
        __syncthreads();                          // prev group's readers done
        // stage this group's 5 W slices
#pragma unroll
        for (int kk = 0; kk < KG; ++kk)
            stage_w(wt, ge * KG + kk, &lds_w[kk * 4096], tid);
        // probe 5 consecutive cells: dz,dy fixed per group, dx = -2..2
        const int dz = ge / 5 - 2, dy = ge % 5 - 2;
        const int nz = z + dz, ny = y + dy;
        const bool rowok = live && ((unsigned)nz < 128u) && ((unsigned)ny < 128u);
        const int base = (nz << 14) | (ny << 7);
#pragma unroll
        for (int kk = 0; kk < KG; ++kk) {
            int nx = x + kk - 2;
            int j = NVOX;
            if (rowok && ((unsigned)nx < 128u)) {
                int t = idx_map[base | nx];
                if (t >= 0) j = t;
            }
            lds_nbr[kk * 256 + slot] = j;
        }
        __syncthreads();                          // stage + nbr visible

        // explicit 1-deep pipeline: buffer 0 preloaded, buffer (kk+1)&1 filled
        // during kk's MFMA cluster. All indices compile-time under full unroll.
        int    jj[2][4];
        bf16x8 bb[2][8];
        {
            int4 q = *(const int4*)&lds_nbr[wave * 64 + l15 * 4];
            jj[0][0] = q.x; jj[0][1] = q.y; jj[0][2] = q.z; jj[0][3] = q.w;
#pragma unroll
            for (int t = 0; t < 4; ++t) {
                const char* rp = fbp + ((size_t)(unsigned)jj[0][t] << 7) + (g << 4);
                bb[0][t * 2]     = *(const bf16x8*)(rp);
                bb[0][t * 2 + 1] = *(const bf16x8*)(rp + 64);
            }
        }
#pragma unroll
        for (int kk = 0; kk < KG; ++kk) {
            const int cur = kk & 1, nxt = cur ^ 1;
            if (kk + 1 < KG) {                    // issue NEXT kk's gathers first
                int4 q = *(const int4*)&lds_nbr[(kk + 1) * 256 + wave * 64 + l15 * 4];
                jj[nxt][0] = q.x; jj[nxt][1] = q.y; jj[nxt][2] = q.z; jj[nxt][3] = q.w;
#pragma unroll
                for (int t = 0; t < 4; ++t) {
                    const char* rp = fbp + ((size_t)(unsigned)jj[nxt][t] << 7) + (g << 4);
                    bb[nxt][t * 2]     = *(const bf16x8*)(rp);
                    bb[nxt][t * 2 + 1] = *(const bf16x8*)(rp + 64);
                }
            }
            // A fragments from LDS (swizzled, conflict-free)
            const char* wb = (const char*)&lds_w[kk * 4096];
            bf16x8 af0[4], af1[4];
#pragma unroll
            for (int a = 0; a < 4; ++a) {
                af0[a] = *(const bf16x8*)(wb + (((a * 16 + l15) << 7) | sw0));
                af1[a] = *(const bf16x8*)(wb + (((a * 16 + l15) << 7) | sw1));
            }
            // pin loads above the MFMA cluster; compiler then emits counted
            // vmcnt (kk+1 loads stay in flight across kk's MFMAs)
            __builtin_amdgcn_sched_barrier(0);
            __builtin_amdgcn_s_setprio(1);
#pragma unroll
            for (int t = 0; t < 4; ++t) {
                if (__any(jj[cur][t] != NVOX)) {  // wave-uniform zero-tile skip
#pragma unroll
                    for (int a = 0; a < 4; ++a) {
                        acc[a][t] = __builtin_amdgcn_mfma_f32_16x16x32_bf16(af0[a], bb[cur][t * 2],     acc[a][t], 0, 0, 0);
                        acc[a][t] = __builtin_amdgcn_mfma_f32_16x16x32_bf16(af1[a], bb[cur][t * 2 + 1], acc[a][t], 0, 0, 0);
                    }
                }
            }
            __builtin_amdgcn_s_setprio(0);
        }
    }

    // epilogue: scatter rows back to ORIGINAL voxel order (bias cancels under BN)
#pragma unroll
    for (int b = 0; b < 4; ++b) {
        int v = vbase + wave * 64 + b * 16 + l15;
        if (v < NVOX) {
            int o = oldof[v];
#pragma unroll
            for (int a = 0; a < 4; ++a)
                *(f32x4*)(out + (size_t)o * 64 + a * 16 + g * 4) = acc[a][b];
        }
    }

    // BN batch-stat partials over this wave's 64 voxels
    float s1[16], s2[16];
#pragma unroll
    for (int a = 0; a < 4; ++a)
#pragma unroll
        for (int r = 0; r < 4; ++r) {
            float s = 0.f, q = 0.f;
#pragma unroll
            for (int b = 0; b < 4; ++b) { float xv = acc[a][b][r]; s += xv; q += xv * xv; }
            s1[a * 4 + r] = s; s2[a * 4 + r] = q;
        }
#pragma unroll
    for (int m = 1; m < 16; m <<= 1) {
#pragma unroll
        for (int i = 0; i < 16; ++i) {
            s1[i] += __shfl_xor(s1[i], m, 64);
            s2[i] += __shfl_xor(s2[i], m, 64);
        }
    }
    if (l15 == 0) {
#pragma unroll
        for (int a = 0; a < 4; ++a)
#pragma unroll
            for (int r = 0; r < 4; ++r) {
                int co = a * 16 + g * 4 + r;
                atomicAdd(&stats[co],      s1[a * 4 + r]);
                atomicAdd(&stats[64 + co], s2[a * 4 + r]);
            }
    }
}

__global__ __launch_bounds__(256) void finalize_kernel(float* __restrict__ out,
                                                       const float* __restrict__ stats,
                                                       const float* __restrict__ gamma,
                                                       const float* __restrict__ beta) {
    int i = blockIdx.x * 256 + threadIdx.x;
    if (i >= NVOX * 16) return;
    int cg = (i & 15) * 4;
    f32x4 v = *(f32x4*)(out + (size_t)i * 4);
    f32x4 r;
#pragma unroll
    for (int c = 0; c < 4; ++c) {
        int co = cg + c;
        float mean = stats[co] * (1.0f / NVOX);
        float var  = stats[64 + co] * (1.0f / NVOX) - mean * mean;
        float sc   = rsqrtf(var + 1e-5f) * gamma[co];
        float sh   = beta[co] - mean * sc;
        float yv   = v[c] * sc + sh;
        r[c] = yv > 0.f ? yv : expm1f(yv);
    }
    *(f32x4*)(out + (size_t)i * 4) = r;
}

extern "C" void kernel_launch(void* const* d_in, const int* in_sizes, int n_in,
                              void* d_out, int out_size, void* d_ws, size_t ws_size,
                              hipStream_t stream) {
    const float* feats  = (const float*)d_in[0];
    const int*   coords = (const int*)d_in[1];
    const float* Wt     = (const float*)d_in[2];
    // d_in[3] = bias: unused — cancels exactly under training-mode BN
    const float* gamma  = (const float*)d_in[4];
    const float* beta   = (const float*)d_in[5];
    float* out = (float*)d_out;
    char*  ws  = (char*)d_ws;

    unsigned short* wt  = (unsigned short*)(ws + WT_OFF);
    float* stats        = (float*)(ws + STATS_OFF);
    int*   pfx          = (int*)(ws + PFX_OFF);
    int*   oldof        = (int*)(ws + OLD_OFF);
    unsigned short* fb  = (unsigned short*)(ws + FB_OFF);
    int*   idx_map      = (int*)(ws + IDX_OFF);

    hipMemsetAsync(idx_map, 0xFF, (size_t)GRID_LIN * 4, stream);  // -1
    hipMemsetAsync(stats, 0, 128 * 4, stream);

    scatter_kernel<<<(NVOX + 255) / 256, 256, 0, stream>>>(coords, idx_map);
    count_kernel<<<GRID_LIN / 1024, 1024, 0, stream>>>(idx_map, pfx);
    scan_kernel<<<1, 1024, 0, stream>>>(pfx);
    relabel_kernel<<<GRID_LIN / 1024, 1024, 0, stream>>>(pfx, idx_map, oldof);
    prep_kernel<<<(PREP_N + 255) / 256, 256, 0, stream>>>(Wt, feats, oldof, wt, fb);
    conv_kernel<<<784, 256, 0, stream>>>(coords, fb, wt, idx_map, oldof, out, stats);
    finalize_kernel<<<12500, 256, 0, stream>>>(out, stats, gamma, beta);
}